// Round 6
// baseline (218.717 us; speedup 1.0000x reference)
//
#include <hip/hip_runtime.h>

// B=4, C=3, H=W=512, window=5 (fixed by setup_inputs).
#define Bd    4
#define Cc    3
#define Hd    512
#define Wd    512
#define WIN   5
#define PLANE (Hd * Wd)        // 1 MiB per f tap-plane (floats)

typedef float f4 __attribute__((ext_vector_type(4)));

// R6 = MEASUREMENT ROUND: identical kernel to R5, but launched 3x per
// kernel_launch (idempotent). dur_us_delta vs R5 = 2 * K_hot, separating
// kernel time from the harness reset floor (~100-110us of fills/copies).
__global__ __launch_bounds__(128, 3) void filter_layer_kernel(
    const float* __restrict__ x,   // [B,3,H,W]
    const float* __restrict__ f,   // [B,25,H,W]
    float* __restrict__ y)         // [B,3,H,W]
{
    const int h   = blockIdx.x;
    const int b   = blockIdx.y;
    const int px0 = (int)threadIdx.x * 4;        // 0..508

    const float* fb = f + ((size_t)b * (WIN * WIN)) * PLANE
                        + (size_t)h * Wd + px0;
    const float* xbase = x + (size_t)b * Cc * PLANE + px0;

    const bool g0 = (px0 >= 4);          // left-edge guard
    const bool g2 = (px0 <= Wd - 8);     // right-edge guard
    const f4 z = {0.f, 0.f, 0.f, 0.f};

    float acc[Cc][4] = {};

    f4 xa[Cc][3], xn[Cc][3];
    f4 fc[WIN], fn[WIN];

    // ---- Prologue: loads for tap-row i=0 (x row gh = h-2) ----
    {
        const int  gh  = h - 2;
        const bool rok = (gh >= 0);
        #pragma unroll
        for (int c = 0; c < Cc; ++c) {
            const float* xp = xbase + (size_t)c * PLANE + (size_t)gh * Wd;
            xa[c][0] = (rok && g0) ? *(const f4*)(xp - 4) : z;
            xa[c][1] = rok         ? *(const f4*)(xp)     : z;
            xa[c][2] = (rok && g2) ? *(const f4*)(xp + 4) : z;
        }
        #pragma unroll
        for (int j = 0; j < WIN; ++j)
            fc[j] = __builtin_nontemporal_load(
                (const f4*)(fb + (size_t)j * PLANE));
    }

    #pragma unroll 1
    for (int i = 0; i < WIN; ++i) {
        if (i + 1 < WIN) {
            const int  gh  = h + i - 1;              // (i+1) - 2
            const bool rok = (gh >= 0) && (gh < Hd);
            #pragma unroll
            for (int c = 0; c < Cc; ++c) {
                const float* xp = xbase + (size_t)c * PLANE + (size_t)gh * Wd;
                xn[c][0] = (rok && g0) ? *(const f4*)(xp - 4) : z;
                xn[c][1] = rok         ? *(const f4*)(xp)     : z;
                xn[c][2] = (rok && g2) ? *(const f4*)(xp + 4) : z;
            }
            const float* fr = fb + (size_t)(i + 1) * WIN * PLANE;
            #pragma unroll
            for (int j = 0; j < WIN; ++j)
                fn[j] = __builtin_nontemporal_load(
                    (const f4*)(fr + (size_t)j * PLANE));
        }

        #pragma unroll
        for (int c = 0; c < Cc; ++c) {
            float xr[12];
            *(f4*)&xr[0] = xa[c][0];
            *(f4*)&xr[4] = xa[c][1];
            *(f4*)&xr[8] = xa[c][2];
            #pragma unroll
            for (int j = 0; j < WIN; ++j) {
                acc[c][0] += fc[j].x * xr[j + 2];
                acc[c][1] += fc[j].y * xr[j + 3];
                acc[c][2] += fc[j].z * xr[j + 4];
                acc[c][3] += fc[j].w * xr[j + 5];
            }
        }

        #pragma unroll
        for (int c = 0; c < Cc; ++c) {
            xa[c][0] = xn[c][0]; xa[c][1] = xn[c][1]; xa[c][2] = xn[c][2];
        }
        #pragma unroll
        for (int j = 0; j < WIN; ++j) fc[j] = fn[j];
    }

    #pragma unroll
    for (int c = 0; c < Cc; ++c) {
        f4 o = {acc[c][0], acc[c][1], acc[c][2], acc[c][3]};
        __builtin_nontemporal_store(
            o, (f4*)(y + (((size_t)b * Cc + c) * Hd + h) * Wd + px0));
    }
}

extern "C" void kernel_launch(void* const* d_in, const int* in_sizes, int n_in,
                              void* d_out, int out_size, void* d_ws, size_t ws_size,
                              hipStream_t stream) {
    const float* x = (const float*)d_in[0];   // [4,3,512,512] fp32
    const float* f = (const float*)d_in[1];   // [4,25,512,512] fp32
    float* y = (float*)d_out;                 // [4,3,512,512] fp32

    dim3 grid(Hd, Bd);                        // one block per (h, b): 2048
    // 3 idempotent launches: delta vs single-launch isolates kernel time
    // (launches 2-3 run with f/x/y L3-resident -> K_hot).
    filter_layer_kernel<<<grid, dim3(128), 0, stream>>>(x, f, y);
    filter_layer_kernel<<<grid, dim3(128), 0, stream>>>(x, f, y);
    filter_layer_kernel<<<grid, dim3(128), 0, stream>>>(x, f, y);
}

// Round 7
// 163.896 us; speedup vs baseline: 1.3345x; 1.3345x over previous
//
#include <hip/hip_runtime.h>

// B=4, C=3, H=W=512, window=5 (fixed by setup_inputs).
//
// FINAL KERNEL (= R5, reverting R6's 3x-launch measurement probe).
// Roofline accounting (R6 delta method: (218.7-165.1)/2 = 26.8 us/launch):
//   kernel ~= 24-27 us vs 20.6 us floor (130 MB mandatory / 6.3 TB/s)
//   harness reset ~= 138 us/iter (ws-poison fill 61us + f/x restores ~70us)
// => remaining total headroom <= 3%, below round-to-round noise.
#define Bd    4
#define Cc    3
#define Hd    512
#define Wd    512
#define WIN   5
#define PLANE (Hd * Wd)        // 1 MiB per f tap-plane (floats)

typedef float f4 __attribute__((ext_vector_type(4)));

// LDS-free, fully software-pipelined: both the f tap-row stream and the x
// row reads are double-buffered in registers, so iteration i computes with
// values issued at iteration i-1 while i+1's loads are in flight. No
// barriers. 2048 blocks x 128 threads; launch_bounds(128,3) -> 12 waves/CU.
__global__ __launch_bounds__(128, 3) void filter_layer_kernel(
    const float* __restrict__ x,   // [B,3,H,W]
    const float* __restrict__ f,   // [B,25,H,W]
    float* __restrict__ y)         // [B,3,H,W]
{
    const int h   = blockIdx.x;
    const int b   = blockIdx.y;
    const int px0 = (int)threadIdx.x * 4;        // 0..508

    const float* fb = f + ((size_t)b * (WIN * WIN)) * PLANE
                        + (size_t)h * Wd + px0;
    const float* xbase = x + (size_t)b * Cc * PLANE + px0;

    const bool g0 = (px0 >= 4);          // left-edge guard
    const bool g2 = (px0 <= Wd - 8);     // right-edge guard
    const f4 z = {0.f, 0.f, 0.f, 0.f};

    float acc[Cc][4] = {};

    f4 xa[Cc][3], xn[Cc][3];
    f4 fc[WIN], fn[WIN];

    // ---- Prologue: loads for tap-row i=0 (x row gh = h-2) ----
    {
        const int  gh  = h - 2;
        const bool rok = (gh >= 0);
        #pragma unroll
        for (int c = 0; c < Cc; ++c) {
            const float* xp = xbase + (size_t)c * PLANE + (size_t)gh * Wd;
            xa[c][0] = (rok && g0) ? *(const f4*)(xp - 4) : z;
            xa[c][1] = rok         ? *(const f4*)(xp)     : z;
            xa[c][2] = (rok && g2) ? *(const f4*)(xp + 4) : z;
        }
        #pragma unroll
        for (int j = 0; j < WIN; ++j)
            fc[j] = __builtin_nontemporal_load(
                (const f4*)(fb + (size_t)j * PLANE));
    }

    #pragma unroll 1
    for (int i = 0; i < WIN; ++i) {
        // ---- Issue iteration i+1's loads first; they fly during compute ----
        if (i + 1 < WIN) {
            const int  gh  = h + i - 1;              // (i+1) - 2
            const bool rok = (gh >= 0) && (gh < Hd);
            #pragma unroll
            for (int c = 0; c < Cc; ++c) {
                const float* xp = xbase + (size_t)c * PLANE + (size_t)gh * Wd;
                xn[c][0] = (rok && g0) ? *(const f4*)(xp - 4) : z;
                xn[c][1] = rok         ? *(const f4*)(xp)     : z;
                xn[c][2] = (rok && g2) ? *(const f4*)(xp + 4) : z;
            }
            const float* fr = fb + (size_t)(i + 1) * WIN * PLANE;
            #pragma unroll
            for (int j = 0; j < WIN; ++j)
                fn[j] = __builtin_nontemporal_load(
                    (const f4*)(fr + (size_t)j * PLANE));
        }

        // ---- Compute tap-row i from xa/fc (loaded one iteration ago) ----
        #pragma unroll
        for (int c = 0; c < Cc; ++c) {
            float xr[12];
            *(f4*)&xr[0] = xa[c][0];
            *(f4*)&xr[4] = xa[c][1];
            *(f4*)&xr[8] = xa[c][2];
            // acc[c][p] += f[k=i*5+j][px0+p] * x[c][gh][px0+p+j-2]
            // xr index: (p + j - 2) + 4 = p + j + 2
            #pragma unroll
            for (int j = 0; j < WIN; ++j) {
                acc[c][0] += fc[j].x * xr[j + 2];
                acc[c][1] += fc[j].y * xr[j + 3];
                acc[c][2] += fc[j].z * xr[j + 4];
                acc[c][3] += fc[j].w * xr[j + 5];
            }
        }

        // ---- Rotate buffers ----
        #pragma unroll
        for (int c = 0; c < Cc; ++c) {
            xa[c][0] = xn[c][0]; xa[c][1] = xn[c][1]; xa[c][2] = xn[c][2];
        }
        #pragma unroll
        for (int j = 0; j < WIN; ++j) fc[j] = fn[j];
    }

    #pragma unroll
    for (int c = 0; c < Cc; ++c) {
        f4 o = {acc[c][0], acc[c][1], acc[c][2], acc[c][3]};
        __builtin_nontemporal_store(
            o, (f4*)(y + (((size_t)b * Cc + c) * Hd + h) * Wd + px0));
    }
}

extern "C" void kernel_launch(void* const* d_in, const int* in_sizes, int n_in,
                              void* d_out, int out_size, void* d_ws, size_t ws_size,
                              hipStream_t stream) {
    const float* x = (const float*)d_in[0];   // [4,3,512,512] fp32
    const float* f = (const float*)d_in[1];   // [4,25,512,512] fp32
    float* y = (float*)d_out;                 // [4,3,512,512] fp32

    dim3 grid(Hd, Bd);                        // one block per (h, b): 2048
    filter_layer_kernel<<<grid, dim3(128), 0, stream>>>(x, f, y);
}